// Round 3
// baseline (504.635 us; speedup 1.0000x reference)
//
#include <hip/hip_runtime.h>
#include <hip/hip_bf16.h>
#include <math.h>

#define NH     4
#define RD     5
#define WW     49
#define DM     256
#define BATCH  32
#define NTOK   4900
#define GSEG   20
#define SEG    245            // WW*RD tokens per segment

typedef short bf16x8 __attribute__((ext_vector_type(8)));
typedef short bf16x4 __attribute__((ext_vector_type(4)));
typedef float f32x4  __attribute__((ext_vector_type(4)));

__device__ __forceinline__ short f2bf(float f) {
    union { __hip_bfloat16 h; short s; } u;
    u.h = __float2bfloat16(f);
    return u.s;
}

// X tile: [64 tokens][256 d], pitch 256, XOR-swizzle on 8-short granules.
__device__ __forceinline__ int qix(int row, int col) {
    return row * 256 + (col ^ ((row & 7) << 3));
}
// XT tile: [256 d][64 tokens], pitch 64, same-style swizzle. Lives after X.
__device__ __forceinline__ int tix(int d, int j) {
    return 64 * 256 + d * 64 + (j ^ ((d & 7) << 3));
}

// ---------------------------------------------------------------------------
// Pre-convert Wq, Wo (fp32 [256,256]) to bf16.
// ---------------------------------------------------------------------------
__global__ __launch_bounds__(256)
void wcvt(const float* __restrict__ Wq, const float* __restrict__ Wo,
          short* __restrict__ Wqb, short* __restrict__ Wob) {
    int t = blockIdx.x * 256 + threadIdx.x;       // 0..32767 float4 units
    const float* src = (t < 16384) ? Wq : Wo;
    short* dst = (t < 16384) ? Wqb : Wob;
    int i = (t & 16383) * 4;
    float4 v = *(const float4*)(src + i);
    bf16x4 o = { f2bf(v.x), f2bf(v.y), f2bf(v.z), f2bf(v.w) };
    *(bf16x4*)(dst + i) = o;
}

// ---------------------------------------------------------------------------
// Fused: one block per (b,g,r) group. 512 threads = 8 waves (2M x 4N grid).
//   Phase 1: X = bf16(emb[49 strided rows] @ Wq^T + bq) -> LDS (X and XT)
//   Phase 2: attention; head = wv&3 (2 waves/head, 32 rows each)
//   Phase 3: out = O @ Wo^T + bo -> global fp32
// LDS 64 KB -> 2 blocks/CU -> 16 waves/CU (4/SIMD). 3 __syncthreads total.
// Both k-loops depth-1 register double-buffered.
// ---------------------------------------------------------------------------
__global__ __launch_bounds__(512, 4)
void fused(const float* __restrict__ emb, const short* __restrict__ Wqb,
           const float* __restrict__ bq, const short* __restrict__ Wob,
           const float* __restrict__ bo, float* __restrict__ out) {
    __shared__ __align__(16) short sm[64 * 256 + 256 * 64];   // X | XT

    const int tid = threadIdx.x;
    const int wv = tid >> 6, ln = tid & 63, lc = ln & 15, lq = ln >> 4;

    const int bid = blockIdx.x;                   // 3200 = 32*20*5
    const int b = bid / 100;
    const int rem = bid - b * 100;
    const int g = rem / 5, r = rem - (rem / 5) * 5;
    const size_t tok0 = (size_t)b * NTOK + (size_t)g * SEG + r;

    const int wn = (wv & 3) * 64;                 // N-slice / head slice
    const int wm = (wv >> 2) * 32;                // M-half

    // ================= Phase 1: X = bf16(emb @ Wq^T + bq) =================
    {
        const float* ar[2];
        const short* br[4];
        #pragma unroll
        for (int mi = 0; mi < 2; mi++) {
            int t = wm + mi * 16 + lc;
            t = (t > WW - 1) ? (WW - 1) : t;      // clamp pad rows (zeroed later)
            ar[mi] = emb + (tok0 + (size_t)t * RD) * DM + lq * 8;
        }
        #pragma unroll
        for (int ni = 0; ni < 4; ni++)
            br[ni] = Wqb + (size_t)(wn + ni * 16 + lc) * DM + lq * 8;

        f32x4 acc[2][4] = {};
        float4 va[2][2];
        bf16x8 wc[4];
        #pragma unroll
        for (int mi = 0; mi < 2; mi++) {
            va[mi][0] = *(const float4*)(ar[mi]);
            va[mi][1] = *(const float4*)(ar[mi] + 4);
        }
        #pragma unroll
        for (int ni = 0; ni < 4; ni++) wc[ni] = *(const bf16x8*)(br[ni]);

        #pragma unroll
        for (int ks = 0; ks < 8; ks++) {
            float4 vn[2][2];
            bf16x8 wnx[4];
            if (ks < 7) {                          // prefetch k-step ks+1
                const int kn = ks * 32 + 32;
                #pragma unroll
                for (int mi = 0; mi < 2; mi++) {
                    vn[mi][0] = *(const float4*)(ar[mi] + kn);
                    vn[mi][1] = *(const float4*)(ar[mi] + kn + 4);
                }
                #pragma unroll
                for (int ni = 0; ni < 4; ni++)
                    wnx[ni] = *(const bf16x8*)(br[ni] + kn);
            }
            bf16x8 af[2];
            #pragma unroll
            for (int mi = 0; mi < 2; mi++) {
                af[mi] = (bf16x8){ f2bf(va[mi][0].x), f2bf(va[mi][0].y),
                                   f2bf(va[mi][0].z), f2bf(va[mi][0].w),
                                   f2bf(va[mi][1].x), f2bf(va[mi][1].y),
                                   f2bf(va[mi][1].z), f2bf(va[mi][1].w) };
            }
            #pragma unroll
            for (int mi = 0; mi < 2; mi++)
                #pragma unroll
                for (int ni = 0; ni < 4; ni++)
                    acc[mi][ni] = __builtin_amdgcn_mfma_f32_16x16x32_bf16(
                        af[mi], wc[ni], acc[mi][ni], 0, 0, 0);
            if (ks < 7) {
                #pragma unroll
                for (int mi = 0; mi < 2; mi++) {
                    va[mi][0] = vn[mi][0]; va[mi][1] = vn[mi][1];
                }
                #pragma unroll
                for (int ni = 0; ni < 4; ni++) wc[ni] = wnx[ni];
            }
        }
        float bv[4];
        #pragma unroll
        for (int ni = 0; ni < 4; ni++) bv[ni] = bq[wn + ni * 16 + lc];
        // Epilogue: write X and XT; pad rows (t >= 49) get ZEROS.
        #pragma unroll
        for (int mi = 0; mi < 2; mi++)
            #pragma unroll
            for (int rg = 0; rg < 4; rg++) {
                const int t = wm + mi * 16 + lq * 4 + rg;
                #pragma unroll
                for (int ni = 0; ni < 4; ni++) {
                    const int col = wn + ni * 16 + lc;
                    const short s = (t < WW) ? f2bf(acc[mi][ni][rg] + bv[ni])
                                             : (short)0;
                    sm[qix(t, col)] = s;
                    sm[tix(col, t)] = s;
                }
            }
    }
    __syncthreads();

    // ================= Phase 2: attention (head = wv&3, rows wm..wm+31) ====
    {
        const int c0 = wn, m0r = wm;
        bf16x8 xa[2][2], xb[4][2];
        #pragma unroll
        for (int mi = 0; mi < 2; mi++) {
            xa[mi][0] = *(const bf16x8*)&sm[qix(m0r + mi * 16 + lc, c0 + lq * 8)];
            xa[mi][1] = *(const bf16x8*)&sm[qix(m0r + mi * 16 + lc, c0 + 32 + lq * 8)];
        }
        #pragma unroll
        for (int ni = 0; ni < 4; ni++) {
            xb[ni][0] = *(const bf16x8*)&sm[qix(ni * 16 + lc, c0 + lq * 8)];
            xb[ni][1] = *(const bf16x8*)&sm[qix(ni * 16 + lc, c0 + 32 + lq * 8)];
        }
        f32x4 sa[2][4] = {};
        #pragma unroll
        for (int mi = 0; mi < 2; mi++)
            #pragma unroll
            for (int ni = 0; ni < 4; ni++) {
                sa[mi][ni] = __builtin_amdgcn_mfma_f32_16x16x32_bf16(
                    xa[mi][0], xb[ni][0], sa[mi][ni], 0, 0, 0);
                sa[mi][ni] = __builtin_amdgcn_mfma_f32_16x16x32_bf16(
                    xa[mi][1], xb[ni][1], sa[mi][ni], 0, 0, 0);
            }
        __syncthreads();   // all waves' X reads done before P overwrites X

        // softmax rows; P (bf16) written over X[:, c0:c0+64)
        #pragma unroll
        for (int mi = 0; mi < 2; mi++)
            #pragma unroll
            for (int rg = 0; rg < 4; rg++) {
                float s[4];
                float m = -1e30f;
                #pragma unroll
                for (int ni = 0; ni < 4; ni++) {
                    s[ni] = sa[mi][ni][rg] * 0.125f;      // 1/sqrt(64)
                    if (ni * 16 + lc < WW) m = fmaxf(m, s[ni]);
                }
                m = fmaxf(m, __shfl_xor(m, 1));
                m = fmaxf(m, __shfl_xor(m, 2));
                m = fmaxf(m, __shfl_xor(m, 4));
                m = fmaxf(m, __shfl_xor(m, 8));
                float e4[4], l_ = 0.f;
                #pragma unroll
                for (int ni = 0; ni < 4; ni++) {
                    e4[ni] = (ni * 16 + lc < WW) ? __expf(s[ni] - m) : 0.f;
                    l_ += e4[ni];
                }
                l_ += __shfl_xor(l_, 1);
                l_ += __shfl_xor(l_, 2);
                l_ += __shfl_xor(l_, 4);
                l_ += __shfl_xor(l_, 8);
                const float inv = 1.f / l_;
                const int pr = m0r + mi * 16 + lq * 4 + rg;
                #pragma unroll
                for (int ni = 0; ni < 4; ni++)
                    sm[qix(pr, c0 + ni * 16 + lc)] = f2bf(e4[ni] * inv);
            }
        // O = P · X  (A: own P rows — same-wave LDS order; B: XT, untouched)
        bf16x8 pa[2][2], pb[4][2];
        #pragma unroll
        for (int mi = 0; mi < 2; mi++) {
            pa[mi][0] = *(const bf16x8*)&sm[qix(m0r + mi * 16 + lc, c0 + lq * 8)];
            pa[mi][1] = *(const bf16x8*)&sm[qix(m0r + mi * 16 + lc, c0 + 32 + lq * 8)];
        }
        #pragma unroll
        for (int ni = 0; ni < 4; ni++) {
            pb[ni][0] = *(const bf16x8*)&sm[tix(c0 + ni * 16 + lc, lq * 8)];
            pb[ni][1] = *(const bf16x8*)&sm[tix(c0 + ni * 16 + lc, 32 + lq * 8)];
        }
        f32x4 oa[2][4] = {};
        #pragma unroll
        for (int mi = 0; mi < 2; mi++)
            #pragma unroll
            for (int ni = 0; ni < 4; ni++) {
                oa[mi][ni] = __builtin_amdgcn_mfma_f32_16x16x32_bf16(
                    pa[mi][0], pb[ni][0], oa[mi][ni], 0, 0, 0);
                oa[mi][ni] = __builtin_amdgcn_mfma_f32_16x16x32_bf16(
                    pa[mi][1], pb[ni][1], oa[mi][ni], 0, 0, 0);
            }
        // O overwrites P in X[:, c0:c0+64), rows < 49 only (own rows).
        #pragma unroll
        for (int mi = 0; mi < 2; mi++)
            #pragma unroll
            for (int rg = 0; rg < 4; rg++) {
                const int i = m0r + mi * 16 + lq * 4 + rg;
                if (i < WW) {
                    #pragma unroll
                    for (int ni = 0; ni < 4; ni++)
                        sm[qix(i, c0 + ni * 16 + lc)] = f2bf(oa[mi][ni][rg]);
                }
            }
    }
    __syncthreads();

    // ================= Phase 3: out = O @ Wo^T + bo =======================
    {
        const short* br[4];
        #pragma unroll
        for (int ni = 0; ni < 4; ni++)
            br[ni] = Wob + (size_t)(wn + ni * 16 + lc) * DM + lq * 8;
        int trow[2];
        #pragma unroll
        for (int mi = 0; mi < 2; mi++) {
            int t = wm + mi * 16 + lc;
            trow[mi] = (t > WW - 1) ? (WW - 1) : t;   // avoid stale pad rows
        }
        f32x4 acc[2][4] = {};
        bf16x8 wc[4];
        #pragma unroll
        for (int ni = 0; ni < 4; ni++) wc[ni] = *(const bf16x8*)(br[ni]);

        #pragma unroll
        for (int ks = 0; ks < 8; ks++) {
            bf16x8 wnx[4];
            if (ks < 7) {
                #pragma unroll
                for (int ni = 0; ni < 4; ni++)
                    wnx[ni] = *(const bf16x8*)(br[ni] + ks * 32 + 32);
            }
            bf16x8 af[2];
            #pragma unroll
            for (int mi = 0; mi < 2; mi++)
                af[mi] = *(const bf16x8*)&sm[qix(trow[mi], ks * 32 + lq * 8)];
            #pragma unroll
            for (int mi = 0; mi < 2; mi++)
                #pragma unroll
                for (int ni = 0; ni < 4; ni++)
                    acc[mi][ni] = __builtin_amdgcn_mfma_f32_16x16x32_bf16(
                        af[mi], wc[ni], acc[mi][ni], 0, 0, 0);
            if (ks < 7) {
                #pragma unroll
                for (int ni = 0; ni < 4; ni++) wc[ni] = wnx[ni];
            }
        }
        float bv[4];
        #pragma unroll
        for (int ni = 0; ni < 4; ni++) bv[ni] = bo[wn + ni * 16 + lc];
        #pragma unroll
        for (int mi = 0; mi < 2; mi++)
            #pragma unroll
            for (int rg = 0; rg < 4; rg++) {
                const int t = wm + mi * 16 + lq * 4 + rg;
                if (t < WW) {
                    float* op = out + (tok0 + (size_t)t * RD) * DM + wn;
                    #pragma unroll
                    for (int ni = 0; ni < 4; ni++)
                        op[ni * 16 + lc] = acc[mi][ni][rg] + bv[ni];
                }
            }
    }
}

// ---------------------------------------------------------------------------
extern "C" void kernel_launch(void* const* d_in, const int* in_sizes, int n_in,
                              void* d_out, int out_size, void* d_ws, size_t ws_size,
                              hipStream_t stream) {
    const float* emb = (const float*)d_in[0];
    const float* Wq  = (const float*)d_in[1];
    const float* bq  = (const float*)d_in[2];
    const float* Wo  = (const float*)d_in[3];
    const float* bo  = (const float*)d_in[4];
    float* out = (float*)d_out;

    // Workspace: Wq bf16 (128 KB) | Wo bf16 (128 KB)
    short* Wqb = (short*)d_ws;
    short* Wob = Wqb + DM * DM;

    wcvt<<<dim3(128), dim3(256), 0, stream>>>(Wq, Wo, Wqb, Wob);
    fused<<<dim3(BATCH * GSEG * RD), dim3(512), 0, stream>>>(
        emb, Wqb, bq, Wob, bo, out);
}

// Round 4
// 421.703 us; speedup vs baseline: 1.1967x; 1.1967x over previous
//
#include <hip/hip_runtime.h>
#include <hip/hip_bf16.h>
#include <math.h>

#define NH     4
#define RD     5
#define WW     49
#define DM     256
#define BATCH  32
#define NTOK   4900
#define GSEG   20
#define SEG    245            // WW*RD tokens per segment

typedef short bf16x8 __attribute__((ext_vector_type(8)));
typedef short bf16x4 __attribute__((ext_vector_type(4)));
typedef float f32x4  __attribute__((ext_vector_type(4)));

__device__ __forceinline__ short f2bf(float f) {
    union { __hip_bfloat16 h; short s; } u;
    u.h = __float2bfloat16(f);
    return u.s;
}

__device__ __forceinline__ void gl_lds16(const void* g, void* l) {
    __builtin_amdgcn_global_load_lds(
        (const __attribute__((address_space(1))) void*)g,
        (__attribute__((address_space(3))) void*)l, 16, 0, 0);
}

// X tile: [64 tokens][256 d] bf16, pitch 256, XOR-swizzle on 8-short granules.
__device__ __forceinline__ int qix(int row, int col) {
    return row * 256 + (col ^ ((row & 7) << 3));
}
// XT tile: [256 d][64 tokens] bf16, pitch 64, same-style swizzle.
__device__ __forceinline__ int tix(int d, int j) {
    return 64 * 256 + d * 64 + (j ^ ((d & 7) << 3));
}

// ---------------------------------------------------------------------------
// Pre-convert Wq, Wo (fp32 [256,256]) to bf16.
// ---------------------------------------------------------------------------
__global__ __launch_bounds__(256)
void wcvt(const float* __restrict__ Wq, const float* __restrict__ Wo,
          short* __restrict__ Wqb, short* __restrict__ Wob) {
    int t = blockIdx.x * 256 + threadIdx.x;       // 0..32767 float4 units
    const float* src = (t < 16384) ? Wq : Wo;
    short* dst = (t < 16384) ? Wqb : Wob;
    int i = (t & 16383) * 4;
    float4 v = *(const float4*)(src + i);
    bf16x4 o = { f2bf(v.x), f2bf(v.y), f2bf(v.z), f2bf(v.w) };
    *(bf16x4*)(dst + i) = o;
}

// ---------------------------------------------------------------------------
// Fused: one block per (b,g,r). 256 threads = 4 waves, one head per wave.
//   Phase 0: stage 49 emb rows fp32 -> LDS via global_load_lds (async, no VGPRs)
//   Phase 1: X = bf16(emb @ Wq^T + bq); A from LDS, weights depth-2 prefetch
//   Phase 2: per-wave head attention, barrier-free
//   Phase 3: out = O @ Wo^T + bo
// LDS 64 KB (A-stage fp32 aliases X|XT; reclaimed after k-loop barrier)
// -> 2 blocks/CU. launch_bounds(256,2): no VGPR squeeze (LDS caps occupancy).
// ---------------------------------------------------------------------------
__global__ __launch_bounds__(256, 2)
void fused(const float* __restrict__ emb, const short* __restrict__ Wqb,
           const float* __restrict__ bq, const short* __restrict__ Wob,
           const float* __restrict__ bo, float* __restrict__ out) {
    __shared__ __align__(16) short sm[64 * 256 + 64 * 256];   // 64 KB
    float* As = (float*)sm;                                   // phase-1 alias

    const int tid = threadIdx.x;
    const int wv = tid >> 6, ln = tid & 63, lc = ln & 15, lq = ln >> 4;

    const int bid = blockIdx.x;                   // 3200 = 32*20*5
    const int b = bid / 100;
    const int rem = bid - b * 100;
    const int g = rem / 5, r = rem - (rem / 5) * 5;
    const size_t tok0 = (size_t)b * NTOK + (size_t)g * SEG + r;
    const int wn = wv * 64;                       // wave's N-slice / head slice

    // ============ Phase 0: async-stage emb rows 0..48 (fp32) =============
    // LDS dest linear (row p at byte p*1024, lane l -> 16B chunk l).
    // Global src pre-swizzled: chunk_g = l ^ ((p&7)<<1)  (even mask -> b128-
    // contiguous pairs survive on the read side). Involution: read applies
    // the same XOR.
    for (int p = wv; p < WW; p += 4)
        gl_lds16(emb + (tok0 + (size_t)p * RD) * DM +
                     (size_t)((ln ^ ((p & 7) << 1)) << 2),
                 (char*)sm + p * 1024);
    // bias loads issued here to hide their latency
    float bvq = bq[wn + lc];   // placeholder touch; real loads below per ni
    __syncthreads();   // drains vmcnt -> A-stage valid

    // ============ Phase 1: k-loop, A from LDS, weights depth-2 ============
    f32x4 acc[4][4] = {};
    {
        const short* br[4];
        #pragma unroll
        for (int ni = 0; ni < 4; ni++)
            br[ni] = Wqb + (size_t)(wn + ni * 16 + lc) * DM + lq * 8;
        bf16x8 wb[2][4];
        #pragma unroll
        for (int ni = 0; ni < 4; ni++) wb[0][ni] = *(const bf16x8*)(br[ni]);
        #pragma unroll
        for (int ni = 0; ni < 4; ni++) wb[1][ni] = *(const bf16x8*)(br[ni] + 32);

        #pragma unroll
        for (int ks = 0; ks < 8; ks++) {
            bf16x8 af[4];
            #pragma unroll
            for (int mi = 0; mi < 4; mi++) {
                const int t = mi * 16 + lc;   // rows >= 49: stale LDS, masked later
                const int fo = t * 256 + (((ks * 8 + lq * 2) ^ ((t & 7) << 1)) << 2);
                float4 lo = *(const float4*)&As[fo];
                float4 hi = *(const float4*)&As[fo + 4];
                af[mi] = (bf16x8){ f2bf(lo.x), f2bf(lo.y), f2bf(lo.z), f2bf(lo.w),
                                   f2bf(hi.x), f2bf(hi.y), f2bf(hi.z), f2bf(hi.w) };
            }
            #pragma unroll
            for (int mi = 0; mi < 4; mi++)
                #pragma unroll
                for (int ni = 0; ni < 4; ni++)
                    acc[mi][ni] = __builtin_amdgcn_mfma_f32_16x16x32_bf16(
                        af[mi], wb[ks & 1][ni], acc[mi][ni], 0, 0, 0);
            if (ks < 6) {
                #pragma unroll
                for (int ni = 0; ni < 4; ni++)
                    wb[ks & 1][ni] = *(const bf16x8*)(br[ni] + (ks + 2) * 32);
            }
        }
    }
    __syncthreads();   // A-stage dead everywhere -> X|XT region writable

    // ============ Phase-1 epilogue: write X and XT (pads zeroed) ==========
    {
        float bv[4];
        #pragma unroll
        for (int ni = 0; ni < 4; ni++) bv[ni] = bq[wn + ni * 16 + lc];
        #pragma unroll
        for (int mi = 0; mi < 4; mi++)
            #pragma unroll
            for (int rg = 0; rg < 4; rg++) {
                const int t = mi * 16 + lq * 4 + rg;
                #pragma unroll
                for (int ni = 0; ni < 4; ni++) {
                    const int col = wn + ni * 16 + lc;
                    const short s = (t < WW) ? f2bf(acc[mi][ni][rg] + bv[ni])
                                             : (short)0;
                    sm[qix(t, col)] = s;
                    sm[tix(col, t)] = s;
                }
            }
    }
    __syncthreads();

    // ============ Phase 2: attention, one wave per head (barrier-free) ====
    {
        const int c0 = wn;
        bf16x8 xa[4][2];
        #pragma unroll
        for (int mi = 0; mi < 4; mi++) {
            xa[mi][0] = *(const bf16x8*)&sm[qix(mi * 16 + lc, c0 + lq * 8)];
            xa[mi][1] = *(const bf16x8*)&sm[qix(mi * 16 + lc, c0 + 32 + lq * 8)];
        }
        f32x4 sa[4][4] = {};
        #pragma unroll
        for (int mi = 0; mi < 4; mi++)
            #pragma unroll
            for (int ni = 0; ni < 4; ni++) {
                sa[mi][ni] = __builtin_amdgcn_mfma_f32_16x16x32_bf16(
                    xa[mi][0], xa[ni][0], sa[mi][ni], 0, 0, 0);
                sa[mi][ni] = __builtin_amdgcn_mfma_f32_16x16x32_bf16(
                    xa[mi][1], xa[ni][1], sa[mi][ni], 0, 0, 0);
            }
        // softmax rows; P (bf16) written over X[:, c0:c0+64)
        #pragma unroll
        for (int mi = 0; mi < 4; mi++)
            #pragma unroll
            for (int rg = 0; rg < 4; rg++) {
                float s[4];
                float m = -1e30f;
                #pragma unroll
                for (int ni = 0; ni < 4; ni++) {
                    s[ni] = sa[mi][ni][rg] * 0.125f;      // 1/sqrt(64)
                    if (ni * 16 + lc < WW) m = fmaxf(m, s[ni]);
                }
                m = fmaxf(m, __shfl_xor(m, 1));
                m = fmaxf(m, __shfl_xor(m, 2));
                m = fmaxf(m, __shfl_xor(m, 4));
                m = fmaxf(m, __shfl_xor(m, 8));
                float e4[4], l_ = 0.f;
                #pragma unroll
                for (int ni = 0; ni < 4; ni++) {
                    e4[ni] = (ni * 16 + lc < WW) ? __expf(s[ni] - m) : 0.f;
                    l_ += e4[ni];
                }
                l_ += __shfl_xor(l_, 1);
                l_ += __shfl_xor(l_, 2);
                l_ += __shfl_xor(l_, 4);
                l_ += __shfl_xor(l_, 8);
                const float inv = 1.f / l_;
                const int pr = mi * 16 + lq * 4 + rg;
                #pragma unroll
                for (int ni = 0; ni < 4; ni++)
                    sm[qix(pr, c0 + ni * 16 + lc)] = f2bf(e4[ni] * inv);
            }
        // O = P · X  (A: own P rows, same-wave LDS order; B: XT)
        bf16x8 pa[4][2], pb[4][2];
        #pragma unroll
        for (int mi = 0; mi < 4; mi++) {
            pa[mi][0] = *(const bf16x8*)&sm[qix(mi * 16 + lc, c0 + lq * 8)];
            pa[mi][1] = *(const bf16x8*)&sm[qix(mi * 16 + lc, c0 + 32 + lq * 8)];
        }
        #pragma unroll
        for (int ni = 0; ni < 4; ni++) {
            pb[ni][0] = *(const bf16x8*)&sm[tix(c0 + ni * 16 + lc, lq * 8)];
            pb[ni][1] = *(const bf16x8*)&sm[tix(c0 + ni * 16 + lc, 32 + lq * 8)];
        }
        f32x4 oa[4][4] = {};
        #pragma unroll
        for (int mi = 0; mi < 4; mi++)
            #pragma unroll
            for (int ni = 0; ni < 4; ni++) {
                oa[mi][ni] = __builtin_amdgcn_mfma_f32_16x16x32_bf16(
                    pa[mi][0], pb[ni][0], oa[mi][ni], 0, 0, 0);
                oa[mi][ni] = __builtin_amdgcn_mfma_f32_16x16x32_bf16(
                    pa[mi][1], pb[ni][1], oa[mi][ni], 0, 0, 0);
            }
        // O overwrites P in X[:, c0:c0+64), rows < 49 only.
        #pragma unroll
        for (int mi = 0; mi < 4; mi++)
            #pragma unroll
            for (int rg = 0; rg < 4; rg++) {
                const int i = mi * 16 + lq * 4 + rg;
                if (i < WW) {
                    #pragma unroll
                    for (int ni = 0; ni < 4; ni++)
                        sm[qix(i, c0 + ni * 16 + lc)] = f2bf(oa[mi][ni][rg]);
                }
            }
    }
    __syncthreads();

    // ============ Phase 3: out = O @ Wo^T + bo (weights depth-2) ==========
    {
        const short* br[4];
        #pragma unroll
        for (int ni = 0; ni < 4; ni++)
            br[ni] = Wob + (size_t)(wn + ni * 16 + lc) * DM + lq * 8;
        int trow[4];
        #pragma unroll
        for (int mi = 0; mi < 4; mi++) {
            int t = mi * 16 + lc;
            trow[mi] = (t > WW - 1) ? (WW - 1) : t;   // avoid stale pad rows
        }
        f32x4 ac3[4][4] = {};
        bf16x8 wb[2][4];
        #pragma unroll
        for (int ni = 0; ni < 4; ni++) wb[0][ni] = *(const bf16x8*)(br[ni]);
        #pragma unroll
        for (int ni = 0; ni < 4; ni++) wb[1][ni] = *(const bf16x8*)(br[ni] + 32);

        #pragma unroll
        for (int ks = 0; ks < 8; ks++) {
            bf16x8 af[4];
            #pragma unroll
            for (int mi = 0; mi < 4; mi++)
                af[mi] = *(const bf16x8*)&sm[qix(trow[mi], ks * 32 + lq * 8)];
            #pragma unroll
            for (int mi = 0; mi < 4; mi++)
                #pragma unroll
                for (int ni = 0; ni < 4; ni++)
                    ac3[mi][ni] = __builtin_amdgcn_mfma_f32_16x16x32_bf16(
                        af[mi], wb[ks & 1][ni], ac3[mi][ni], 0, 0, 0);
            if (ks < 6) {
                #pragma unroll
                for (int ni = 0; ni < 4; ni++)
                    wb[ks & 1][ni] = *(const bf16x8*)(br[ni] + (ks + 2) * 32);
            }
        }
        float bv[4];
        #pragma unroll
        for (int ni = 0; ni < 4; ni++) bv[ni] = bo[wn + ni * 16 + lc];
        #pragma unroll
        for (int mi = 0; mi < 4; mi++)
            #pragma unroll
            for (int rg = 0; rg < 4; rg++) {
                const int t = mi * 16 + lq * 4 + rg;
                if (t < WW) {
                    float* op = out + (tok0 + (size_t)t * RD) * DM + wn;
                    #pragma unroll
                    for (int ni = 0; ni < 4; ni++)
                        op[ni * 16 + lc] = ac3[mi][ni][rg] + bv[ni];
                }
            }
    }
    (void)bvq;
}

// ---------------------------------------------------------------------------
extern "C" void kernel_launch(void* const* d_in, const int* in_sizes, int n_in,
                              void* d_out, int out_size, void* d_ws, size_t ws_size,
                              hipStream_t stream) {
    const float* emb = (const float*)d_in[0];
    const float* Wq  = (const float*)d_in[1];
    const float* bq  = (const float*)d_in[2];
    const float* Wo  = (const float*)d_in[3];
    const float* bo  = (const float*)d_in[4];
    float* out = (float*)d_out;

    // Workspace: Wq bf16 (128 KB) | Wo bf16 (128 KB)
    short* Wqb = (short*)d_ws;
    short* Wob = Wqb + DM * DM;

    wcvt<<<dim3(128), dim3(256), 0, stream>>>(Wq, Wo, Wqb, Wob);
    fused<<<dim3(BATCH * GSEG * RD), dim3(256), 0, stream>>>(
        emb, Wqb, bq, Wob, bo, out);
}

// Round 6
// 378.651 us; speedup vs baseline: 1.3327x; 1.1137x over previous
//
#include <hip/hip_runtime.h>
#include <hip/hip_bf16.h>
#include <math.h>

#define NH     4
#define RD     5
#define WW     49
#define DM     256
#define BATCH  32
#define NTOK   4900
#define GSEG   20
#define SEG    245            // WW*RD tokens per segment

typedef short bf16x8 __attribute__((ext_vector_type(8)));
typedef short bf16x4 __attribute__((ext_vector_type(4)));
typedef float f32x4  __attribute__((ext_vector_type(4)));

__device__ __forceinline__ short f2bf(float f) {
    union { __hip_bfloat16 h; short s; } u;
    u.h = __float2bfloat16(f);
    return u.s;
}

__device__ __forceinline__ void gl_lds16(const void* g, void* l) {
    __builtin_amdgcn_global_load_lds(
        (const __attribute__((address_space(1))) void*)g,
        (__attribute__((address_space(3))) void*)l, 16, 0, 0);
}

// X tile: [64 tokens][256 d] bf16, pitch 256, XOR-swizzle on 8-short granules.
__device__ __forceinline__ int qix(int row, int col) {
    return row * 256 + (col ^ ((row & 7) << 3));
}
// XT tile: [256 d][64 tokens] bf16, pitch 64, same-style swizzle.
__device__ __forceinline__ int tix(int d, int j) {
    return 64 * 256 + d * 64 + (j ^ ((d & 7) << 3));
}

// ---------------------------------------------------------------------------
// Pre-convert Wq, Wo (fp32 [256,256]) to bf16.
// ---------------------------------------------------------------------------
__global__ __launch_bounds__(256)
void wcvt(const float* __restrict__ Wq, const float* __restrict__ Wo,
          short* __restrict__ Wqb, short* __restrict__ Wob) {
    int t = blockIdx.x * 256 + threadIdx.x;       // 0..32767 float4 units
    const float* src = (t < 16384) ? Wq : Wo;
    short* dst = (t < 16384) ? Wqb : Wob;
    int i = (t & 16383) * 4;
    float4 v = *(const float4*)(src + i);
    bf16x4 o = { f2bf(v.x), f2bf(v.y), f2bf(v.z), f2bf(v.w) };
    *(bf16x4*)(dst + i) = o;
}

// ---------------------------------------------------------------------------
// Fused: one block per (b,g,r). 256 threads = 4 waves, one head per wave.
//   Phase 0: stage 49 emb rows fp32 -> LDS (global_load_lds, 3-bit chunk swz)
//   Phase 1: X = bf16(emb @ Wq^T + bq); A from LDS (conflict-free reads)
//   Phase 2: attention; symmetric-S softmax (lane-local + 2 shfl)
//   Phase 3: out = O @ Wo^T + bo
// LDS 64 KB (A-stage fp32 aliases X|XT) -> 2 blocks/CU.
// ---------------------------------------------------------------------------
__global__ __launch_bounds__(256, 2)
void fused(const float* __restrict__ emb, const short* __restrict__ Wqb,
           const float* __restrict__ bq, const short* __restrict__ Wob,
           const float* __restrict__ bo, float* __restrict__ out) {
    __shared__ __align__(16) short sm[64 * 256 + 64 * 256];   // 64 KB
    float* As = (float*)sm;                                   // phase-1 alias

    const int tid = threadIdx.x;
    const int wv = tid >> 6, ln = tid & 63, lc = ln & 15, lq = ln >> 4;

    const int bid = blockIdx.x;                   // 3200 = 32*20*5
    const int b = bid / 100;
    const int rem = bid - b * 100;
    const int g = rem / 5, r = rem - (rem / 5) * 5;
    const size_t tok0 = (size_t)b * NTOK + (size_t)g * SEG + r;
    const int wn = wv * 64;                       // wave's N-slice / head slice

    // ============ Phase 0: async-stage emb rows 0..48 (fp32) =============
    // LDS dest linear (row p at byte p*1024, lane ln -> chunk ln).
    // Global chunk = ln ^ (p&7): full 3-bit XOR -> conflict-free reads.
    for (int p = wv; p < WW; p += 4)
        gl_lds16(emb + (tok0 + (size_t)p * RD) * DM +
                     (size_t)((ln ^ (p & 7)) << 2),
                 (char*)sm + p * 1024);
    __syncthreads();   // drains vmcnt -> A-stage valid

    // ============ Phase 1: k-loop, A from LDS, weights depth-2 ============
    f32x4 acc[4][4] = {};
    {
        const short* br[4];
        #pragma unroll
        for (int ni = 0; ni < 4; ni++)
            br[ni] = Wqb + (size_t)(wn + ni * 16 + lc) * DM + lq * 8;
        bf16x8 wb[2][4];
        #pragma unroll
        for (int ni = 0; ni < 4; ni++) wb[0][ni] = *(const bf16x8*)(br[ni]);
        #pragma unroll
        for (int ni = 0; ni < 4; ni++) wb[1][ni] = *(const bf16x8*)(br[ni] + 32);

        #pragma unroll
        for (int ks = 0; ks < 8; ks++) {
            bf16x8 af[4];
            #pragma unroll
            for (int mi = 0; mi < 4; mi++) {
                const int t = mi * 16 + lc;   // rows >= 49: stale LDS, masked later
                const int clo = (ks * 8 + lq * 2) ^ (t & 7);
                float4 lo = *(const float4*)&As[t * 256 + clo * 4];
                float4 hi = *(const float4*)&As[t * 256 + (clo ^ 1) * 4];
                af[mi] = (bf16x8){ f2bf(lo.x), f2bf(lo.y), f2bf(lo.z), f2bf(lo.w),
                                   f2bf(hi.x), f2bf(hi.y), f2bf(hi.z), f2bf(hi.w) };
            }
            #pragma unroll
            for (int mi = 0; mi < 4; mi++)
                #pragma unroll
                for (int ni = 0; ni < 4; ni++)
                    acc[mi][ni] = __builtin_amdgcn_mfma_f32_16x16x32_bf16(
                        af[mi], wb[ks & 1][ni], acc[mi][ni], 0, 0, 0);
            if (ks < 6) {
                #pragma unroll
                for (int ni = 0; ni < 4; ni++)
                    wb[ks & 1][ni] = *(const bf16x8*)(br[ni] + (ks + 2) * 32);
            }
        }
    }
    __syncthreads();   // A-stage dead everywhere -> X|XT region writable

    // ============ Phase-1 epilogue: write X and XT (pads zeroed) ==========
    {
        float bv[4];
        #pragma unroll
        for (int ni = 0; ni < 4; ni++) bv[ni] = bq[wn + ni * 16 + lc];
        #pragma unroll
        for (int mi = 0; mi < 4; mi++)
            #pragma unroll
            for (int rg = 0; rg < 4; rg++) {
                const int t = mi * 16 + lq * 4 + rg;
                #pragma unroll
                for (int ni = 0; ni < 4; ni++) {
                    const int col = wn + ni * 16 + lc;
                    const short s = (t < WW) ? f2bf(acc[mi][ni][rg] + bv[ni])
                                             : (short)0;
                    sm[qix(t, col)] = s;
                    sm[tix(col, t)] = s;
                }
            }
    }
    __syncthreads();

    // ============ Phase 2: attention, one wave per head (barrier-free) ====
    {
        const int c0 = wn;
        bf16x8 xa[4][2];
        #pragma unroll
        for (int mi = 0; mi < 4; mi++) {
            xa[mi][0] = *(const bf16x8*)&sm[qix(mi * 16 + lc, c0 + lq * 8)];
            xa[mi][1] = *(const bf16x8*)&sm[qix(mi * 16 + lc, c0 + 32 + lq * 8)];
        }
        // sa[mi][ni][rg] = S[j = 16mi+4lq+rg][i = 16ni+lc]   (S symmetric)
        f32x4 sa[4][4] = {};
        #pragma unroll
        for (int mi = 0; mi < 4; mi++)
            #pragma unroll
            for (int ni = 0; ni < 4; ni++) {
                sa[mi][ni] = __builtin_amdgcn_mfma_f32_16x16x32_bf16(
                    xa[mi][0], xa[ni][0], sa[mi][ni], 0, 0, 0);
                sa[mi][ni] = __builtin_amdgcn_mfma_f32_16x16x32_bf16(
                    xa[mi][1], xa[ni][1], sa[mi][ni], 0, 0, 0);
            }
        // scale in place
        #pragma unroll
        for (int mi = 0; mi < 4; mi++)
            #pragma unroll
            for (int ni = 0; ni < 4; ni++)
                #pragma unroll
                for (int rg = 0; rg < 4; rg++)
                    sa[mi][ni][rg] *= 0.125f;     // 1/sqrt(64)

        // Softmax over j (row axis of sa) for each column i = 16ni+lc.
        // Lane-local: 16 j's; cross-lane: only lq groups -> shfl_xor 16,32.
        const int jb = lq * 4;
        #pragma unroll
        for (int ni = 0; ni < 4; ni++) {
            float m = -1e30f;
            #pragma unroll
            for (int mi = 0; mi < 4; mi++)
                #pragma unroll
                for (int rg = 0; rg < 4; rg++) {
                    const float v = (16 * mi + rg + jb < WW) ? sa[mi][ni][rg]
                                                             : -1e30f;
                    m = fmaxf(m, v);
                }
            m = fmaxf(m, __shfl_xor(m, 16));
            m = fmaxf(m, __shfl_xor(m, 32));
            float l_ = 0.f;
            #pragma unroll
            for (int mi = 0; mi < 4; mi++)
                #pragma unroll
                for (int rg = 0; rg < 4; rg++) {
                    const float e = (16 * mi + rg + jb < WW)
                                        ? __expf(sa[mi][ni][rg] - m) : 0.f;
                    sa[mi][ni][rg] = e;
                    l_ += e;
                }
            l_ += __shfl_xor(l_, 16);
            l_ += __shfl_xor(l_, 32);
            const float inv = 1.f / l_;
            const int i = 16 * ni + lc;           // P row (query token)
            #pragma unroll
            for (int mi = 0; mi < 4; mi++) {
                bf16x4 w = { f2bf(sa[mi][ni][0] * inv), f2bf(sa[mi][ni][1] * inv),
                             f2bf(sa[mi][ni][2] * inv), f2bf(sa[mi][ni][3] * inv) };
                *(bf16x4*)&sm[qix(i, c0 + 16 * mi + jb)] = w;   // P over X slice
            }
        }
        // O = P · X  (A: P rows from X slice; B: XT)
        bf16x8 pa[4][2], pb[4][2];
        #pragma unroll
        for (int mi = 0; mi < 4; mi++) {
            pa[mi][0] = *(const bf16x8*)&sm[qix(mi * 16 + lc, c0 + lq * 8)];
            pa[mi][1] = *(const bf16x8*)&sm[qix(mi * 16 + lc, c0 + 32 + lq * 8)];
        }
        #pragma unroll
        for (int ni = 0; ni < 4; ni++) {
            pb[ni][0] = *(const bf16x8*)&sm[tix(c0 + ni * 16 + lc, lq * 8)];
            pb[ni][1] = *(const bf16x8*)&sm[tix(c0 + ni * 16 + lc, 32 + lq * 8)];
        }
        f32x4 oa[4][4] = {};
        #pragma unroll
        for (int mi = 0; mi < 4; mi++)
            #pragma unroll
            for (int ni = 0; ni < 4; ni++) {
                oa[mi][ni] = __builtin_amdgcn_mfma_f32_16x16x32_bf16(
                    pa[mi][0], pb[ni][0], oa[mi][ni], 0, 0, 0);
                oa[mi][ni] = __builtin_amdgcn_mfma_f32_16x16x32_bf16(
                    pa[mi][1], pb[ni][1], oa[mi][ni], 0, 0, 0);
            }
        // O overwrites P in X[:, c0:c0+64), rows < 49 only.
        #pragma unroll
        for (int mi = 0; mi < 4; mi++)
            #pragma unroll
            for (int rg = 0; rg < 4; rg++) {
                const int i = mi * 16 + lq * 4 + rg;
                if (i < WW) {
                    #pragma unroll
                    for (int ni = 0; ni < 4; ni++)
                        sm[qix(i, c0 + ni * 16 + lc)] = f2bf(oa[mi][ni][rg]);
                }
            }
    }
    __syncthreads();

    // ============ Phase 3: out = O @ Wo^T + bo (weights depth-2) ==========
    {
        const short* br[4];
        #pragma unroll
        for (int ni = 0; ni < 4; ni++)
            br[ni] = Wob + (size_t)(wn + ni * 16 + lc) * DM + lq * 8;
        int trow[4];
        #pragma unroll
        for (int mi = 0; mi < 4; mi++) {
            int t = mi * 16 + lc;
            trow[mi] = (t > WW - 1) ? (WW - 1) : t;   // avoid stale pad rows
        }
        f32x4 ac3[4][4] = {};
        bf16x8 wb[2][4];
        #pragma unroll
        for (int ni = 0; ni < 4; ni++) wb[0][ni] = *(const bf16x8*)(br[ni]);
        #pragma unroll
        for (int ni = 0; ni < 4; ni++) wb[1][ni] = *(const bf16x8*)(br[ni] + 32);

        #pragma unroll
        for (int ks = 0; ks < 8; ks++) {
            bf16x8 af[4];
            #pragma unroll
            for (int mi = 0; mi < 4; mi++)
                af[mi] = *(const bf16x8*)&sm[qix(trow[mi], ks * 32 + lq * 8)];
            #pragma unroll
            for (int mi = 0; mi < 4; mi++)
                #pragma unroll
                for (int ni = 0; ni < 4; ni++)
                    ac3[mi][ni] = __builtin_amdgcn_mfma_f32_16x16x32_bf16(
                        af[mi], wb[ks & 1][ni], ac3[mi][ni], 0, 0, 0);
            if (ks < 6) {
                #pragma unroll
                for (int ni = 0; ni < 4; ni++)
                    wb[ks & 1][ni] = *(const bf16x8*)(br[ni] + (ks + 2) * 32);
            }
        }
        float bv[4];
        #pragma unroll
        for (int ni = 0; ni < 4; ni++) bv[ni] = bo[wn + ni * 16 + lc];
        #pragma unroll
        for (int mi = 0; mi < 4; mi++)
            #pragma unroll
            for (int rg = 0; rg < 4; rg++) {
                const int t = mi * 16 + lq * 4 + rg;
                if (t < WW) {
                    float* op = out + (tok0 + (size_t)t * RD) * DM + wn;
                    #pragma unroll
                    for (int ni = 0; ni < 4; ni++)
                        op[ni * 16 + lc] = ac3[mi][ni][rg] + bv[ni];
                }
            }
    }
}

// ---------------------------------------------------------------------------
extern "C" void kernel_launch(void* const* d_in, const int* in_sizes, int n_in,
                              void* d_out, int out_size, void* d_ws, size_t ws_size,
                              hipStream_t stream) {
    const float* emb = (const float*)d_in[0];
    const float* Wq  = (const float*)d_in[1];
    const float* bq  = (const float*)d_in[2];
    const float* Wo  = (const float*)d_in[3];
    const float* bo  = (const float*)d_in[4];
    float* out = (float*)d_out;

    // Workspace: Wq bf16 (128 KB) | Wo bf16 (128 KB)
    short* Wqb = (short*)d_ws;
    short* Wob = Wqb + DM * DM;

    wcvt<<<dim3(128), dim3(256), 0, stream>>>(Wq, Wo, Wqb, Wob);
    fused<<<dim3(BATCH * GSEG * RD), dim3(256), 0, stream>>>(
        emb, Wqb, bq, Wob, bo, out);
}